// Round 2
// baseline (4668.412 us; speedup 1.0000x reference)
//
#include <hip/hip_runtime.h>

typedef _Float16 half8 __attribute__((ext_vector_type(8)));
typedef float    f32x4 __attribute__((ext_vector_type(4)));

#define B_   1024
#define T_   256
#define U_   512

// d_ws layout
static const size_t WHT_OFF = 0;                 // WhT fp16 [2048][512]   = 2 MB
static const size_t H_OFF   = 2u*1024*1024;      // h ping-pong fp16 [2][1024][512] = 2 MB
static const size_t CTR_OFF = 4u*1024*1024;      // counters [16][256] u32 = 16 KB

// Transpose + fp16-convert Wh: WhT[j][k] = Wh[k][j]
__global__ __launch_bounds__(512)
void prep_wht(const float* __restrict__ Wh, _Float16* __restrict__ WhT) {
  int j = blockIdx.x;   // 0..2047 (output col of Wh)
  int k = threadIdx.x;  // 0..511
  WhT[(size_t)j*U_ + k] = (_Float16)Wh[(size_t)k*(4*U_) + j];
}

__device__ __forceinline__ float sigm(float x) { return 1.f/(1.f + __expf(-x)); }
__device__ __forceinline__ float tanhf_fast(float x) {
  float ax = fabsf(x);
  float e  = __expf(2.f*ax);           // large ax -> inf -> t = 1 (safe)
  float t  = 1.f - 2.f/(e + 1.f);
  return copysignf(t, x);
}

// Persistent LSTM: grid 256 WGs x 256 thr. WG (grp,jcw): rows [grp*64,+64), u [jcw*32,+32).
// Wave v (0..3) computes gate v for the slab. Wh slab lives in VGPRs as B-fragments.
__global__ __launch_bounds__(256, 1)
void lstm_persist(const float* __restrict__ prices,
                  const float* __restrict__ Wx,
                  const float* __restrict__ bias,
                  const float* __restrict__ Wd,
                  const float* __restrict__ bd,
                  const float* __restrict__ Wp,
                  const float* __restrict__ bp,
                  const _Float16* __restrict__ WhT,
                  _Float16* __restrict__ hbuf,      // [2][1024][512] fp16
                  unsigned int* __restrict__ ctr,   // [16][256]
                  float* __restrict__ out)          // [1024][32]
{
  // 64 rows x 512 k, pad +8 halves: row stride 1040 B (16B aligned, 2-way banks = free)
  __shared__ __align__(16) _Float16 hs[64][520];      // 66.6 KB
  __shared__ __align__(16) float    gz[4][64][33];    // 33.8 KB (gate z slabs)
  __shared__ float ps[64];                            // prices column

  const int tid = threadIdx.x;
  const int w   = blockIdx.x;
  const int grp = w >> 4;          // batch group 0..15
  const int jcw = w & 15;          // u-block 0..15
  const int row0 = grp * 64;
  const int u0   = jcw * 32;
  const int wv   = tid >> 6;       // wave id == gate id
  const int ln   = tid & 15;
  const int qd   = (tid >> 4) & 3; // quad within wave

  // ---- Load Wh slab once into registers as MFMA B-fragments ----
  // B[k][n]: lane holds n = ln, k = kk*32 + qd*8 + j  ->  WhT[col][k] contiguous
  half8 bf[16][2];
  #pragma unroll
  for (int kk = 0; kk < 16; ++kk) {
    #pragma unroll
    for (int ct = 0; ct < 2; ++ct) {
      int col = wv*U_ + u0 + ct*16 + ln;   // global gate-col
      bf[kk][ct] = *(const half8*)&WhT[(size_t)col*U_ + kk*32 + qd*8];
    }
  }

  // gate-stage mapping: thread owns (rows rg*8+e, u = u0+ul)
  const int ul = tid & 31;
  const int rg = tid >> 5;         // 0..7
  const int u  = u0 + ul;
  float wxv[4], bv[4];
  #pragma unroll
  for (int g = 0; g < 4; ++g) { wxv[g] = Wx[g*U_ + u]; bv[g] = bias[g*U_ + u]; }

  float c[8];
  #pragma unroll
  for (int e = 0; e < 8; ++e) c[e] = 0.f;

  unsigned int* myctr = ctr + grp*T_;

  for (int t = 0; t < T_; ++t) {
    const _Float16* hcur = hbuf + (size_t)(t & 1)*(B_*U_) + (size_t)row0*U_;
    _Float16* hnxt = hbuf + (size_t)((t + 1) & 1)*(B_*U_);

    // ---- stage h tile (64 rows x 512 halves = 64 KB = 4096 x 16B chunks) ----
    if (tid < 64) ps[tid] = prices[(size_t)(row0 + tid)*T_ + t];
    #pragma unroll
    for (int it = 0; it < 16; ++it) {
      int id = tid + it*256;       // 0..4095 chunks of 16 B
      int r  = id >> 6;            // row 0..63
      int ch = id & 63;            // 16B chunk within row, 0..63
      *(half8*)&hs[r][ch*8] = *(const half8*)&hcur[(size_t)r*U_ + ch*8];
    }
    __syncthreads();

    // ---- z = h @ Wh for this wave's gate, 64x32 cols, K=512 ----
    f32x4 acc[4][2];
    #pragma unroll
    for (int rt = 0; rt < 4; ++rt)
      #pragma unroll
      for (int ct = 0; ct < 2; ++ct)
        #pragma unroll
        for (int r = 0; r < 4; ++r)
          acc[rt][ct][r] = 0.f;

    #pragma unroll
    for (int kk = 0; kk < 16; ++kk) {
      half8 afr[4];
      #pragma unroll
      for (int rt = 0; rt < 4; ++rt)   // A[m=ln][k=qd*8+j]
        afr[rt] = *(const half8*)&hs[rt*16 + ln][kk*32 + qd*8];
      #pragma unroll
      for (int rt = 0; rt < 4; ++rt) {
        acc[rt][0] = __builtin_amdgcn_mfma_f32_16x16x32_f16(afr[rt], bf[kk][0], acc[rt][0], 0, 0, 0);
        acc[rt][1] = __builtin_amdgcn_mfma_f32_16x16x32_f16(afr[rt], bf[kk][1], acc[rt][1], 0, 0, 0);
      }
    }

    // ---- scatter gate z to LDS (C/D layout: row = qd*4+r, col = ln) ----
    #pragma unroll
    for (int rt = 0; rt < 4; ++rt)
      #pragma unroll
      for (int ct = 0; ct < 2; ++ct)
        #pragma unroll
        for (int r = 0; r < 4; ++r)
          gz[wv][rt*16 + qd*4 + r][ct*16 + ln] = acc[rt][ct][r];
    __syncthreads();

    // ---- gate math (fp32), c in registers, write h fp16 ----
    #pragma unroll
    for (int e = 0; e < 8; ++e) {
      int r = rg*8 + e;
      float px = ps[r];
      float zi = gz[0][r][ul] + px*wxv[0] + bv[0];
      float zf = gz[1][r][ul] + px*wxv[1] + bv[1];
      float zg = gz[2][r][ul] + px*wxv[2] + bv[2];
      float zo = gz[3][r][ul] + px*wxv[3] + bv[3];
      float ig = sigm(zi), fg = sigm(zf), gg = tanhf_fast(zg), og = sigm(zo);
      float cn = fg*c[e] + ig*gg;
      c[e] = cn;
      float hh = og*tanhf_fast(cn);
      hnxt[(size_t)(row0 + r)*U_ + u] = (_Float16)hh;
    }

    // ---- per-group device-scope barrier (16 WGs, fresh counter per step) ----
    __syncthreads();
    if (tid == 0) {
      __hip_atomic_fetch_add(&myctr[t], 1u, __ATOMIC_RELEASE, __HIP_MEMORY_SCOPE_AGENT);
      while (__hip_atomic_load(&myctr[t], __ATOMIC_ACQUIRE, __HIP_MEMORY_SCOPE_AGENT) < 16u)
        __builtin_amdgcn_s_sleep(8);
    }
    __syncthreads();
  }

  // ---- fused head: this WG handles 4 rows: row0 + jcw*4 .. +4 ----
  {
    const _Float16* hfin = hbuf;                               // parity of t=256 is 0
    float*    xrow = (float*)&gz[0][0][0];                     // [4][64] (reuse LDS)
    _Float16* hrow = (_Float16*)((char*)&gz[0][0][0] + 1024);  // [4][512]

    int rr = tid >> 6;     // 0..3: row within the 4
    int kk = tid & 63;     // hidden-64 index
    int brow = row0 + jcw*4 + rr;
    {
      int fl = tid*8;      // stage 4 rows x 512 halves
      int r2 = fl >> 9;
      int of = fl & 511;
      *(half8*)&hrow[r2*U_ + of] =
        *(const half8*)&hfin[(size_t)(row0 + jcw*4 + r2)*U_ + of];
    }
    __syncthreads();
    float a = bd[kk];
    for (int k2 = 0; k2 < U_; ++k2)
      a += (float)hrow[rr*U_ + k2] * Wd[(size_t)k2*64 + kk];
    a = fmaxf(a, 0.f);
    xrow[rr*64 + kk] = a;
    __syncthreads();
    if (kk < 32) {
      float o2 = bp[kk];
      #pragma unroll
      for (int j2 = 0; j2 < 64; ++j2)
        o2 += xrow[rr*64 + j2] * Wp[j2*32 + kk];
      out[(size_t)brow*32 + kk] = o2;
    }
  }
}

extern "C" void kernel_launch(void* const* d_in, const int* in_sizes, int n_in,
                              void* d_out, int out_size, void* d_ws, size_t ws_size,
                              hipStream_t stream) {
  (void)in_sizes; (void)n_in; (void)out_size; (void)ws_size;
  const float* prices = (const float*)d_in[0];
  const float* Wx     = (const float*)d_in[1];
  const float* Wh     = (const float*)d_in[2];
  const float* bias   = (const float*)d_in[3];
  const float* Wd     = (const float*)d_in[4];
  const float* bd     = (const float*)d_in[5];
  const float* Wp     = (const float*)d_in[6];
  const float* bp     = (const float*)d_in[7];

  char* ws = (char*)d_ws;
  _Float16* WhT      = (_Float16*)(ws + WHT_OFF);
  _Float16* hbuf     = (_Float16*)(ws + H_OFF);
  unsigned int* ctr  = (unsigned int*)(ws + CTR_OFF);

  // zero initial h (buffer 0) and the barrier counters (ws is poisoned each call)
  hipMemsetAsync(hbuf, 0, (size_t)B_*U_*sizeof(_Float16), stream);
  hipMemsetAsync(ctr, 0, 16*T_*sizeof(unsigned int), stream);

  prep_wht<<<dim3(4*U_), dim3(U_), 0, stream>>>(Wh, WhT);
  lstm_persist<<<dim3(256), dim3(256), 0, stream>>>(prices, Wx, bias, Wd, bd, Wp, bp,
                                                    WhT, hbuf, ctr, (float*)d_out);
}

// Round 3
// 3312.523 us; speedup vs baseline: 1.4093x; 1.4093x over previous
//
#include <hip/hip_runtime.h>

typedef _Float16 half8 __attribute__((ext_vector_type(8)));
typedef float    f32x4 __attribute__((ext_vector_type(4)));

#define B_   1024
#define T_   256
#define U_   512

// d_ws layout
static const size_t WHT_OFF = 0;                 // WhT fp16 [2048][512]   = 2 MB
static const size_t H_OFF   = 2u*1024*1024;      // h ping-pong fp16 [2][1024][512] = 2 MB
static const size_t CTR_OFF = 4u*1024*1024;      // counters [16][256] u32 = 16 KB

// Transpose + fp16-convert Wh: WhT[j][k] = Wh[k][j]
__global__ __launch_bounds__(512)
void prep_wht(const float* __restrict__ Wh, _Float16* __restrict__ WhT) {
  int j = blockIdx.x;   // 0..2047 (output col of Wh)
  int k = threadIdx.x;  // 0..511
  WhT[(size_t)j*U_ + k] = (_Float16)Wh[(size_t)k*(4*U_) + j];
}

__device__ __forceinline__ float sigm(float x) { return 1.f/(1.f + __expf(-x)); }
__device__ __forceinline__ float tanhf_fast(float x) {
  float ax = fabsf(x);
  float e  = __expf(2.f*ax);           // large ax -> inf -> t = 1 (safe)
  float t  = 1.f - 2.f/(e + 1.f);
  return copysignf(t, x);
}

// Persistent LSTM: 256 WGs x 512 thr (8 waves/CU for latency hiding).
// Group mapping is XCD-local (round-robin b%8 heuristic): grp's 16 WGs share one XCD's L2
// so the per-step h exchange avoids the Infinity fabric. Correctness does NOT depend on it
// (agent-scope atomics retained).
// WG (grp,jcw): rows [grp*64,+64), u [jcw*32,+32). Wave w: gate g=w&3, col-half ch=w>>2.
__global__ __launch_bounds__(512, 1)
void lstm_persist(const float* __restrict__ prices,
                  const float* __restrict__ Wx,
                  const float* __restrict__ bias,
                  const float* __restrict__ Wd,
                  const float* __restrict__ bd,
                  const float* __restrict__ Wp,
                  const float* __restrict__ bp,
                  const _Float16* __restrict__ WhT,
                  _Float16* __restrict__ hbuf,      // [2][1024][512] fp16
                  unsigned int* __restrict__ ctr,   // [16][256]
                  float* __restrict__ out)          // [1024][32]
{
  __shared__ __align__(16) _Float16 hs[64][520];      // 66.6 KB (stride 1040B, 16B-aligned)
  __shared__ __align__(16) float    gz[4][64][33];    // 33.8 KB
  __shared__ float ps[64];

  const int tid = threadIdx.x;
  const int b   = blockIdx.x;
  // XCD-local swizzle: b = slot*8 + xcd ; grp = xcd*2 + (slot&1) ; jcw = slot>>1
  const int xcd  = b & 7;
  const int slot = b >> 3;            // 0..31
  const int grp  = xcd*2 + (slot & 1);
  const int jcw  = slot >> 1;         // 0..15
  const int row0 = grp * 64;
  const int u0   = jcw * 32;

  const int wv8 = tid >> 6;        // wave 0..7
  const int g   = wv8 & 3;         // gate
  const int chw = wv8 >> 2;        // column half 0..1 (16 cols each)
  const int ln  = tid & 15;
  const int qd  = (tid >> 4) & 3;  // quad within wave

  // ---- Load Wh slab once into registers as MFMA B-fragments (64 VGPRs) ----
  // B[k][n]: lane holds n = ln, k = kk*32 + qd*8 + j
  half8 bf[16];
  #pragma unroll
  for (int kk = 0; kk < 16; ++kk) {
    int col = g*U_ + u0 + chw*16 + ln;
    bf[kk] = *(const half8*)&WhT[(size_t)col*U_ + kk*32 + qd*8];
  }

  // gate-stage mapping: thread owns (rows rg*4+e, u = u0+ul)
  const int ul = tid & 31;
  const int rg = tid >> 5;         // 0..15
  const int u  = u0 + ul;
  float wxv[4], bv[4];
  #pragma unroll
  for (int gg2 = 0; gg2 < 4; ++gg2) { wxv[gg2] = Wx[gg2*U_ + u]; bv[gg2] = bias[gg2*U_ + u]; }

  float c[4];
  #pragma unroll
  for (int e = 0; e < 4; ++e) c[e] = 0.f;

  unsigned int* myctr = ctr + grp*T_;

  for (int t = 0; t < T_; ++t) {
    const _Float16* hcur = hbuf + (size_t)(t & 1)*(B_*U_) + (size_t)row0*U_;
    _Float16* hnxt = hbuf + (size_t)((t + 1) & 1)*(B_*U_);

    // ---- stage h tile (64 rows x 512 halves = 4096 x 16B chunks) ----
    if (tid < 64) ps[tid] = prices[(size_t)(row0 + tid)*T_ + t];
    #pragma unroll
    for (int it = 0; it < 8; ++it) {
      int id = tid + it*512;       // 0..4095
      int r  = id >> 6;            // row 0..63
      int ch = id & 63;            // 16B chunk in row
      *(half8*)&hs[r][ch*8] = *(const half8*)&hcur[(size_t)r*U_ + ch*8];
    }
    __syncthreads();

    // ---- z = h @ Wh: this wave does gate g, cols [chw*16,+16), all 64 rows, K=512 ----
    f32x4 acc[4];
    #pragma unroll
    for (int rt = 0; rt < 4; ++rt)
      #pragma unroll
      for (int r = 0; r < 4; ++r)
        acc[rt][r] = 0.f;

    #pragma unroll
    for (int kk = 0; kk < 16; ++kk) {
      #pragma unroll
      for (int rt = 0; rt < 4; ++rt) {
        half8 afr = *(const half8*)&hs[rt*16 + ln][kk*32 + qd*8];  // A[m=ln][k=qd*8+j]
        acc[rt] = __builtin_amdgcn_mfma_f32_16x16x32_f16(afr, bf[kk], acc[rt], 0, 0, 0);
      }
    }

    // ---- scatter gate z to LDS (C/D: row = qd*4+r, col = ln) ----
    #pragma unroll
    for (int rt = 0; rt < 4; ++rt)
      #pragma unroll
      for (int r = 0; r < 4; ++r)
        gz[g][rt*16 + qd*4 + r][chw*16 + ln] = acc[rt][r];
    __syncthreads();

    // ---- gate math (fp32), c in registers, write h fp16 ----
    #pragma unroll
    for (int e = 0; e < 4; ++e) {
      int r = rg*4 + e;
      float px = ps[r];
      float zi = gz[0][r][ul] + px*wxv[0] + bv[0];
      float zf = gz[1][r][ul] + px*wxv[1] + bv[1];
      float zg = gz[2][r][ul] + px*wxv[2] + bv[2];
      float zo = gz[3][r][ul] + px*wxv[3] + bv[3];
      float ig = sigm(zi), fg = sigm(zf), gg = tanhf_fast(zg), og = sigm(zo);
      float cn = fg*c[e] + ig*gg;
      c[e] = cn;
      float hh = og*tanhf_fast(cn);
      hnxt[(size_t)(row0 + r)*U_ + u] = (_Float16)hh;
    }

    // ---- per-group barrier (16 WGs, fresh counter per step) ----
    __syncthreads();
    if (tid == 0) {
      __hip_atomic_fetch_add(&myctr[t], 1u, __ATOMIC_RELEASE, __HIP_MEMORY_SCOPE_AGENT);
      while (__hip_atomic_load(&myctr[t], __ATOMIC_ACQUIRE, __HIP_MEMORY_SCOPE_AGENT) < 16u)
        __builtin_amdgcn_s_sleep(2);
    }
    __syncthreads();
  }

  // ---- fused head: this WG handles 4 rows: row0 + jcw*4 .. +4 ----
  {
    const _Float16* hfin = hbuf;                               // parity of t=256 is 0
    float*    xrow = (float*)&gz[0][0][0];                     // [4][64]
    _Float16* hrow = (_Float16*)((char*)&gz[0][0][0] + 1024);  // [4][512]

    if (tid < 256) {
      int fl = tid*8;      // stage 4 rows x 512 halves
      int r2 = fl >> 9;
      int of = fl & 511;
      *(half8*)&hrow[r2*U_ + of] =
        *(const half8*)&hfin[(size_t)(row0 + jcw*4 + r2)*U_ + of];
    }
    __syncthreads();
    if (tid < 256) {
      int rr = tid >> 6;   // 0..3
      int kk = tid & 63;
      float a = bd[kk];
      for (int k2 = 0; k2 < U_; ++k2)
        a += (float)hrow[rr*U_ + k2] * Wd[(size_t)k2*64 + kk];
      a = fmaxf(a, 0.f);
      xrow[rr*64 + kk] = a;
    }
    __syncthreads();
    if (tid < 256 && (tid & 63) < 32) {
      int rr = tid >> 6;
      int kk = tid & 63;
      int brow = row0 + jcw*4 + rr;
      float o2 = bp[kk];
      #pragma unroll
      for (int j2 = 0; j2 < 64; ++j2)
        o2 += xrow[rr*64 + j2] * Wp[j2*32 + kk];
      out[(size_t)brow*32 + kk] = o2;
    }
  }
}

extern "C" void kernel_launch(void* const* d_in, const int* in_sizes, int n_in,
                              void* d_out, int out_size, void* d_ws, size_t ws_size,
                              hipStream_t stream) {
  (void)in_sizes; (void)n_in; (void)out_size; (void)ws_size;
  const float* prices = (const float*)d_in[0];
  const float* Wx     = (const float*)d_in[1];
  const float* Wh     = (const float*)d_in[2];
  const float* bias   = (const float*)d_in[3];
  const float* Wd     = (const float*)d_in[4];
  const float* bd     = (const float*)d_in[5];
  const float* Wp     = (const float*)d_in[6];
  const float* bp     = (const float*)d_in[7];

  char* ws = (char*)d_ws;
  _Float16* WhT      = (_Float16*)(ws + WHT_OFF);
  _Float16* hbuf     = (_Float16*)(ws + H_OFF);
  unsigned int* ctr  = (unsigned int*)(ws + CTR_OFF);

  hipMemsetAsync(hbuf, 0, (size_t)B_*U_*sizeof(_Float16), stream);
  hipMemsetAsync(ctr, 0, 16*T_*sizeof(unsigned int), stream);

  prep_wht<<<dim3(4*U_), dim3(U_), 0, stream>>>(Wh, WhT);
  lstm_persist<<<dim3(256), dim3(512), 0, stream>>>(prices, Wx, bias, Wd, bd, Wp, bp,
                                                    WhT, hbuf, ctr, (float*)d_out);
}

// Round 4
// 2089.199 us; speedup vs baseline: 2.2345x; 1.5855x over previous
//
#include <hip/hip_runtime.h>

typedef _Float16 half8 __attribute__((ext_vector_type(8)));
typedef float    f32x4 __attribute__((ext_vector_type(4)));

#define B_   1024
#define T_   256
#define U_   512

// d_ws layout
static const size_t WHT_OFF = 0;                 // WhT fp16 [2048][512]   = 2 MB
static const size_t H_OFF   = 2u*1024*1024;      // h ping-pong fp16 [2][1024][512] = 2 MB
static const size_t CTR_OFF = 4u*1024*1024;      // counters [16][256] u32 = 16 KB

// Transpose + fp16-convert Wh: WhT[j][k] = Wh[k][j]
__global__ __launch_bounds__(512)
void prep_wht(const float* __restrict__ Wh, _Float16* __restrict__ WhT) {
  int j = blockIdx.x;   // 0..2047 (output col of Wh)
  int k = threadIdx.x;  // 0..511
  WhT[(size_t)j*U_ + k] = (_Float16)Wh[(size_t)k*(4*U_) + j];
}

__device__ __forceinline__ float sigm(float x) { return 1.f/(1.f + __expf(-x)); }
__device__ __forceinline__ float tanhf_fast(float x) {
  float ax = fabsf(x);
  float e  = __expf(2.f*ax);           // large ax -> inf -> t = 1 (safe)
  float t  = 1.f - 2.f/(e + 1.f);
  return copysignf(t, x);
}

// Fine-grained agent-coherent (sc1) access helpers — NO bulk L2 wb/inv.
__device__ __forceinline__ unsigned long long ld_agent_u64(const void* p) {
  return __hip_atomic_load((const unsigned long long*)p,
                           __ATOMIC_RELAXED, __HIP_MEMORY_SCOPE_AGENT);
}
__device__ __forceinline__ void st_agent_u32(void* p, unsigned v) {
  __hip_atomic_store((unsigned*)p, v, __ATOMIC_RELAXED, __HIP_MEMORY_SCOPE_AGENT);
}

// Persistent LSTM: 256 WGs x 512 thr. WG (grp,jcw): rows [grp*64,+64), u [jcw*32,+32).
// Wave w: gate g=w&3, col-half ch=w>>2. Wh slab stays in VGPRs.
// Cross-WG h exchange via sc1 write-through stores + sc1 loads (Infinity-Cache coherent);
// barrier = relaxed agent fetch_add + relaxed spin. No release/acquire bulk cache ops.
__global__ __launch_bounds__(512, 1)
void lstm_persist(const float* __restrict__ prices,
                  const float* __restrict__ Wx,
                  const float* __restrict__ bias,
                  const float* __restrict__ Wd,
                  const float* __restrict__ bd,
                  const float* __restrict__ Wp,
                  const float* __restrict__ bp,
                  const _Float16* __restrict__ WhT,
                  _Float16* __restrict__ hbuf,      // [2][1024][512] fp16
                  unsigned int* __restrict__ ctr,   // [16][256]
                  float* __restrict__ out)          // [1024][32]
{
  __shared__ __align__(16) _Float16 hs[64][520];      // 66.6 KB (stride 1040B)
  __shared__ __align__(16) float    gz[4][64][33];    // 33.8 KB
  __shared__ float ps[64];

  const int tid = threadIdx.x;
  const int b   = blockIdx.x;
  // XCD-local swizzle (speed heuristic only): b = slot*8 + xcd
  const int xcd  = b & 7;
  const int slot = b >> 3;            // 0..31
  const int grp  = xcd*2 + (slot & 1);
  const int jcw  = slot >> 1;         // 0..15
  const int row0 = grp * 64;
  const int u0   = jcw * 32;

  const int wv8 = tid >> 6;        // wave 0..7
  const int g   = wv8 & 3;         // gate
  const int chw = wv8 >> 2;        // column half 0..1
  const int ln  = tid & 15;
  const int qd  = (tid >> 4) & 3;  // quad within wave

  // ---- Wh slab -> B-fragments (64 VGPRs): B[k=kk*32+qd*8+j][n=ln] ----
  half8 bf[16];
  #pragma unroll
  for (int kk = 0; kk < 16; ++kk) {
    int col = g*U_ + u0 + chw*16 + ln;
    bf[kk] = *(const half8*)&WhT[(size_t)col*U_ + kk*32 + qd*8];
  }

  // gate-stage mapping: thread owns rows {rw*2, rw*2+1} x u cols {u, u+1}
  const int up = tid & 15;
  const int rw = tid >> 4;         // 0..31
  const int u  = u0 + up*2;
  float wxv[4][2], bv[4][2];
  #pragma unroll
  for (int gg2 = 0; gg2 < 4; ++gg2)
    #pragma unroll
    for (int j = 0; j < 2; ++j) {
      wxv[gg2][j] = Wx[gg2*U_ + u + j];
      bv[gg2][j]  = bias[gg2*U_ + u + j];
    }

  float c[2][2];
  c[0][0] = c[0][1] = c[1][0] = c[1][1] = 0.f;

  unsigned int* myctr = ctr + grp*T_;

  for (int t = 0; t < T_; ++t) {
    const _Float16* hcur = hbuf + (size_t)(t & 1)*(B_*U_) + (size_t)row0*U_;
    _Float16* hnxt = hbuf + (size_t)((t + 1) & 1)*(B_*U_);

    // ---- stage h tile via sc1 8B loads: 64 rows x 128 chunks of 8B ----
    if (tid < 64) ps[tid] = prices[(size_t)(row0 + tid)*T_ + t];
    #pragma unroll
    for (int it = 0; it < 16; ++it) {
      int id = tid + it*512;       // 0..8191
      int r  = id >> 7;            // row 0..63
      int ch = id & 127;           // 8B chunk in row
      unsigned long long v = ld_agent_u64(&hcur[(size_t)r*U_ + ch*4]);
      *(unsigned long long*)&hs[r][ch*4] = v;
    }
    __syncthreads();

    // ---- z = h @ Wh: gate g, cols [chw*16,+16), 64 rows, K=512 ----
    f32x4 acc[4];
    #pragma unroll
    for (int rt = 0; rt < 4; ++rt)
      #pragma unroll
      for (int r = 0; r < 4; ++r)
        acc[rt][r] = 0.f;

    #pragma unroll
    for (int kk = 0; kk < 16; ++kk) {
      #pragma unroll
      for (int rt = 0; rt < 4; ++rt) {
        half8 afr = *(const half8*)&hs[rt*16 + ln][kk*32 + qd*8];  // A[m=ln][k=qd*8+j]
        acc[rt] = __builtin_amdgcn_mfma_f32_16x16x32_f16(afr, bf[kk], acc[rt], 0, 0, 0);
      }
    }

    // ---- scatter z to LDS (C/D: row = qd*4+r, col = ln) ----
    #pragma unroll
    for (int rt = 0; rt < 4; ++rt)
      #pragma unroll
      for (int r = 0; r < 4; ++r)
        gz[g][rt*16 + qd*4 + r][chw*16 + ln] = acc[rt][r];
    __syncthreads();

    // ---- gate math (fp32); h written as packed 2xfp16 sc1 stores ----
    #pragma unroll
    for (int e = 0; e < 2; ++e) {
      int r = rw*2 + e;
      float px = ps[r];
      unsigned short hb[2];
      #pragma unroll
      for (int j = 0; j < 2; ++j) {
        float zi = gz[0][r][up*2+j] + px*wxv[0][j] + bv[0][j];
        float zf = gz[1][r][up*2+j] + px*wxv[1][j] + bv[1][j];
        float zg = gz[2][r][up*2+j] + px*wxv[2][j] + bv[2][j];
        float zo = gz[3][r][up*2+j] + px*wxv[3][j] + bv[3][j];
        float ig = sigm(zi), fg = sigm(zf), gg = tanhf_fast(zg), og = sigm(zo);
        float cn = fg*c[e][j] + ig*gg;
        c[e][j] = cn;
        _Float16 hh = (_Float16)(og*tanhf_fast(cn));
        hb[j] = __builtin_bit_cast(unsigned short, hh);
      }
      unsigned pk = (unsigned)hb[0] | ((unsigned)hb[1] << 16);
      st_agent_u32(&hnxt[(size_t)(row0 + r)*U_ + u], pk);
    }

    // ---- per-group barrier: relaxed agent RMW + relaxed spin ----
    // (__syncthreads drains each wave's vmcnt -> sc1 h stores are at IC before the add)
    __syncthreads();
    if (tid == 0) {
      __hip_atomic_fetch_add(&myctr[t], 1u, __ATOMIC_RELAXED, __HIP_MEMORY_SCOPE_AGENT);
      while (__hip_atomic_load(&myctr[t], __ATOMIC_RELAXED, __HIP_MEMORY_SCOPE_AGENT) < 16u)
        __builtin_amdgcn_s_sleep(1);
    }
    __syncthreads();
  }

  // ---- fused head: 4 rows: row0 + jcw*4 .. +4 ----
  {
    const _Float16* hfin = hbuf;                               // parity of t=256 is 0
    float*    xrow = (float*)&gz[0][0][0];                     // [4][64]
    _Float16* hrow = (_Float16*)((char*)&gz[0][0][0] + 1024);  // [4][512]

    {
      int fl = tid*4;      // 512 threads x 8B = 4 rows x 512 halves
      int r2 = fl >> 9;
      int of = fl & 511;
      unsigned long long v = ld_agent_u64(&hfin[(size_t)(row0 + jcw*4 + r2)*U_ + of]);
      *(unsigned long long*)&hrow[r2*U_ + of] = v;
    }
    __syncthreads();
    if (tid < 256) {
      int rr = tid >> 6;   // 0..3
      int kk = tid & 63;
      float a = bd[kk];
      for (int k2 = 0; k2 < U_; ++k2)
        a += (float)hrow[rr*U_ + k2] * Wd[(size_t)k2*64 + kk];
      a = fmaxf(a, 0.f);
      xrow[rr*64 + kk] = a;
    }
    __syncthreads();
    if (tid < 256 && (tid & 63) < 32) {
      int rr = tid >> 6;
      int kk = tid & 63;
      int brow = row0 + jcw*4 + rr;
      float o2 = bp[kk];
      #pragma unroll
      for (int j2 = 0; j2 < 64; ++j2)
        o2 += xrow[rr*64 + j2] * Wp[j2*32 + kk];
      out[(size_t)brow*32 + kk] = o2;
    }
  }
}

extern "C" void kernel_launch(void* const* d_in, const int* in_sizes, int n_in,
                              void* d_out, int out_size, void* d_ws, size_t ws_size,
                              hipStream_t stream) {
  (void)in_sizes; (void)n_in; (void)out_size; (void)ws_size;
  const float* prices = (const float*)d_in[0];
  const float* Wx     = (const float*)d_in[1];
  const float* Wh     = (const float*)d_in[2];
  const float* bias   = (const float*)d_in[3];
  const float* Wd     = (const float*)d_in[4];
  const float* bd     = (const float*)d_in[5];
  const float* Wp     = (const float*)d_in[6];
  const float* bp     = (const float*)d_in[7];

  char* ws = (char*)d_ws;
  _Float16* WhT      = (_Float16*)(ws + WHT_OFF);
  _Float16* hbuf     = (_Float16*)(ws + H_OFF);
  unsigned int* ctr  = (unsigned int*)(ws + CTR_OFF);

  hipMemsetAsync(hbuf, 0, (size_t)B_*U_*sizeof(_Float16), stream);
  hipMemsetAsync(ctr, 0, 16*T_*sizeof(unsigned int), stream);

  prep_wht<<<dim3(4*U_), dim3(U_), 0, stream>>>(Wh, WhT);
  lstm_persist<<<dim3(256), dim3(512), 0, stream>>>(prices, Wx, bias, Wd, bd, Wp, bp,
                                                    WhT, hbuf, ctr, (float*)d_out);
}